// Round 7
// baseline (495.792 us; speedup 1.0000x reference)
//
#include <hip/hip_runtime.h>
#include <math.h>
#include <stdint.h>

#define B_ 2
#define H_ 8
#define C_ 2048
#define E_ 1024
#define D_ 64
#define KP_ 8
#define P_ 16
#define HD_ 512              // H*D
#define ROWS_ 32768          // B*H*C
#define M_ 4096              // B*C

typedef __bf16 bf16x8 __attribute__((ext_vector_type(8)));
typedef float f32x4 __attribute__((ext_vector_type(4)));
typedef uint16_t u16x8 __attribute__((ext_vector_type(8)));

__device__ inline uint16_t f2bf(float f) {
    union { float f; uint32_t u; } v; v.f = f;
    uint32_t u = v.u + 0x7FFF + ((v.u >> 16) & 1);   // RNE
    return (uint16_t)(u >> 16);
}
__device__ inline float bf2f(uint16_t h) {
    union { uint32_t u; float f; } v; v.u = ((uint32_t)h) << 16;
    return v.f;
}

// async global->LDS, 16B per lane; LDS dest = wave-uniform base + lane*16
__device__ inline void gload16(const uint16_t* g, uint16_t* l) {
    __builtin_amdgcn_global_load_lds(
        (const __attribute__((address_space(1))) void*)g,
        (__attribute__((address_space(3))) void*)l, 16, 0, 0);
}

// ---------------------------------------------------------------------------
// prep kernel: x-convert, weight transpose-convert, density context-sums.
// ---------------------------------------------------------------------------
__global__ __launch_bounds__(256) void prep_kernel(
    const float* __restrict__ x,
    const float* __restrict__ Wq, const float* __restrict__ Wk,
    const float* __restrict__ Wv, const float* __restrict__ Wu,
    const float* __restrict__ means, const float* __restrict__ sigmas,
    uint16_t* __restrict__ xb, uint16_t* __restrict__ Wall,
    uint16_t* __restrict__ Wut, float* __restrict__ S)
{
    const int bx = blockIdx.x;
    if (bx < 2048) {
        const int i = (bx * 256 + threadIdx.x) * 8;
        const float4 a = *(const float4*)(x + i);
        const float4 b = *(const float4*)(x + i + 4);
        u16x8 o;
        o[0] = f2bf(a.x); o[1] = f2bf(a.y); o[2] = f2bf(a.z); o[3] = f2bf(a.w);
        o[4] = f2bf(b.x); o[5] = f2bf(b.y); o[6] = f2bf(b.z); o[7] = f2bf(b.w);
        *(u16x8*)(xb + i) = o;
        return;
    }
    if (bx < 4096) {
        const int t = bx - 2048;
        const int z = t >> 9;
        const float* in; uint16_t* out; int R, Cc; float scale;
        if (z == 0)      { in = Wq; out = Wall;               R = E_;  Cc = HD_; scale = 0.125f; }
        else if (z == 1) { in = Wk; out = Wall + 512 * 1024;  R = E_;  Cc = HD_; scale = 0.125f; }
        else if (z == 2) { in = Wv; out = Wall + 1024 * 1024; R = E_;  Cc = HD_; scale = 1.0f; }
        else             { in = Wu; out = Wut;                R = HD_; Cc = E_;  scale = 1.0f; }
        const int tiles_x = Cc >> 5;
        const int ti = t & 511;
        const int tx = ti % tiles_x;
        const int ty = ti / tiles_x;
        const int r0 = ty * 32, c0 = tx * 32;
        __shared__ float tbuf[32][33];
        const int lx = threadIdx.x & 31, ly = threadIdx.x >> 5;
#pragma unroll
        for (int i = 0; i < 4; ++i)
            tbuf[ly * 4 + i][lx] = in[(size_t)(r0 + ly * 4 + i) * Cc + c0 + lx];
        __syncthreads();
#pragma unroll
        for (int i = 0; i < 4; ++i)
            out[(size_t)(c0 + ly * 4 + i) * R + r0 + lx] =
                f2bf(tbuf[lx][ly * 4 + i] * scale);
        return;
    }
    // ---- density sums ----
    const int row = (bx - 4096) * 256 + threadIdx.x;
    const int lane = threadIdx.x & 63;
    const int bh = row >> 11;          // constant per block (256 rows/block)

    __shared__ float Sacc[128];
    if (threadIdx.x < 128) Sacc[threadIdx.x] = 0.0f;
    __syncthreads();

    const float* mrow = means + (size_t)row * 8;
    const float* srow = sigmas + (size_t)row * 8;
    const float4 ma = *(const float4*)(mrow);
    const float4 mb = *(const float4*)(mrow + 4);
    const float4 sa = *(const float4*)(srow);
    const float4 sb = *(const float4*)(srow + 4);
    const float mm[8] = {ma.x, ma.y, ma.z, ma.w, mb.x, mb.y, mb.z, mb.w};
    const float sg[8] = {sa.x, sa.y, sa.z, sa.w, sb.x, sb.y, sb.z, sb.w};

    int idx[16];
#pragma unroll
    for (int j = 0; j < 8; ++j) {
        int i0 = (int)floorf(mm[j]);
        i0 = min(max(i0, 0), C_ - 1);
        idx[2 * j] = i0;
        idx[2 * j + 1] = min(i0 + 1, C_ - 1);
    }
    unsigned dupm = 0;
#pragma unroll
    for (int p = 1; p < 16; ++p) {
        bool d = false;
#pragma unroll
        for (int q = 0; q < 15; ++q)
            if (q < p) d = d || (idx[q] == idx[p]);
        if (d) dupm |= (1u << p);
    }

    // lane's final slot after the 6-stage butterfly is bitrev6(lane)
    const int rev = ((lane & 1) << 5) | ((lane & 2) << 3) | ((lane & 4) << 1) |
                    ((lane & 8) >> 1) | ((lane & 16) >> 3) | ((lane & 32) >> 5);

#pragma unroll
    for (int ph = 0; ph < 2; ++ph) {
        float a[64];
#pragma unroll
        for (int j = 0; j < 64; ++j) {
            const int p = ph * 8 + (j >> 3);
            const int kk = j & 7;
            const float fi = (float)idx[p];
            const float t = (fi - mm[kk]) / sg[kk];
            const float e = expf(-0.5f * t * t);
            a[j] = ((dupm >> p) & 1u) ? 0.0f : e;
        }
        // recursive halving butterfly reduce
#pragma unroll
        for (int b = 0; b < 6; ++b) {
            const int n = 32 >> b;
            const bool hi = (lane >> b) & 1;
#pragma unroll
            for (int j = 0; j < n; ++j) {
                float send = hi ? a[j] : a[j + n];
                float recv = __shfl_xor(send, 1 << b);
                a[j] = (hi ? a[j + n] : a[j]) + recv;
            }
        }
        atomicAdd(&Sacc[ph * 64 + rev], a[0]);
    }
    __syncthreads();
    if (threadIdx.x < 128)
        atomicAdd(&S[bh * 128 + threadIdx.x], Sacc[threadIdx.x]);
}

// ---------------------------------------------------------------------------
// Fused QKV GEMM (MFMA bf16), 128x64 tiles, BK=64, double-buffered prefetch.
// ---------------------------------------------------------------------------
__global__ __launch_bounds__(256) void gemm_qkv_kernel(
    const uint16_t* __restrict__ xb, const uint16_t* __restrict__ Wall,
    uint16_t* __restrict__ Qt, uint16_t* __restrict__ Kt,
    uint16_t* __restrict__ Vt)
{
    const int K = E_;                       // 1024
    const int m0 = blockIdx.y * 128;
    const int n0 = blockIdx.x * 64;         // 0..1535
    const int z = n0 >> 9;
    uint16_t* __restrict__ Out = (z == 0) ? Qt : (z == 1) ? Kt : Vt;
    const int h = (n0 & 511) >> 6;          // single head per block

    __shared__ __align__(16) uint16_t smem[24576];   // 48 KB, 3 blocks/CU

    const int tid = threadIdx.x;
    const int w = tid >> 6, lane = tid & 63;

    f32x4 acc[2][4] = {};

    const uint16_t* gP[3];
    uint16_t* lP[3];
#pragma unroll
    for (int j = 0; j < 3; ++j) {
        const int ci = w * 3 + j;
        const int rr = (ci & 7) * 16 + (lane >> 2);   // works for both halves
        const int ko = (lane & 3) * 8;
        if (ci < 8) {
            gP[j] = xb + (size_t)(m0 + rr) * K + ko;
            lP[j] = &smem[ci * 512];
        } else {
            const int cb = ci - 8;
            gP[j] = Wall + (size_t)(n0 + cb * 16 + (lane >> 2)) * K + ko;
            lP[j] = &smem[4096 + cb * 512];
        }
    }

    const int fr = lane & 15;
    const int fk = (lane >> 4) * 8;

    auto stage = [&](int buf, int k0) {
        const int off = buf * 12288;
#pragma unroll
        for (int j = 0; j < 3; ++j) {
            gload16(gP[j] + k0,      lP[j] + off);
            gload16(gP[j] + k0 + 32, lP[j] + off + 6144);
        }
    };

    stage(0, 0);
    __syncthreads();                         // drain prologue loads
    int cur = 0;
    for (int k0 = 0; k0 < K; k0 += 64) {
        if (k0 + 64 < K) stage(cur ^ 1, k0 + 64);
        const int off = cur * 12288;
#pragma unroll
        for (int half = 0; half < 2; ++half) {
            const int base = off + half * 6144;
            bf16x8 af[2], bf[4];
#pragma unroll
            for (int mt = 0; mt < 2; ++mt)
                af[mt] = *(const bf16x8*)&smem[base + (w * 32 + mt * 16 + fr) * 32 + fk];
#pragma unroll
            for (int nt = 0; nt < 4; ++nt)
                bf[nt] = *(const bf16x8*)&smem[base + 4096 + (nt * 16 + fr) * 32 + fk];
#pragma unroll
            for (int mt = 0; mt < 2; ++mt)
#pragma unroll
                for (int nt = 0; nt < 4; ++nt)
                    acc[mt][nt] = __builtin_amdgcn_mfma_f32_16x16x32_bf16(
                        af[mt], bf[nt], acc[mt][nt], 0, 0, 0);
        }
        __syncthreads();
        cur ^= 1;
    }

    // ---- epilogue: stage 128x64 bf16 tile (stride 72), stream coalesced ----
#pragma unroll
    for (int mt = 0; mt < 2; ++mt)
#pragma unroll
        for (int nt = 0; nt < 4; ++nt) {
            const int col = nt * 16 + fr;
#pragma unroll
            for (int r = 0; r < 4; ++r) {
                const int rw = w * 32 + mt * 16 + (lane >> 4) * 4 + r;
                smem[rw * 72 + col] = f2bf(acc[mt][nt][r]);
            }
        }
    __syncthreads();
#pragma unroll
    for (int it = 0; it < 4; ++it) {
        const int j = it * 256 + tid;       // 0..1023 chunks of 8
        const int row = j >> 3, c8 = (j & 7) * 8;
        const int m = m0 + row;
        const int b = m >> 11, c = m & (C_ - 1);
        *(u16x8*)&Out[(((size_t)(b * H_ + h) * C_ + c) << 6) + c8] =
            *(const u16x8*)&smem[row * 72 + c8];
    }
}

// ---------------------------------------------------------------------------
// GEMM 2 (MFMA bf16), 128x64 tiles, BK=64, double-buffered prefetch.
// ---------------------------------------------------------------------------
__global__ __launch_bounds__(256) void gemm_out_kernel(
    const uint16_t* __restrict__ U, const uint16_t* __restrict__ Wut,
    const float* __restrict__ bu, float* __restrict__ out)
{
    const int K = HD_;                      // 512
    const int m0 = blockIdx.y * 128;
    const int n0 = blockIdx.x * 64;         // N=1024

    __shared__ __align__(16) uint16_t smem[24576];   // 48 KB double buffer

    const int tid = threadIdx.x;
    const int w = tid >> 6, lane = tid & 63;

    f32x4 acc[2][4] = {};

    const uint16_t* gP[3];
    uint16_t* lP[3];
#pragma unroll
    for (int j = 0; j < 3; ++j) {
        const int ci = w * 3 + j;
        const int ko = (lane & 3) * 8;
        if (ci < 8) {
            gP[j] = U + (size_t)(m0 + ci * 16 + (lane >> 2)) * K + ko;
            lP[j] = &smem[ci * 512];
        } else {
            const int cb = ci - 8;
            gP[j] = Wut + (size_t)(n0 + cb * 16 + (lane >> 2)) * K + ko;
            lP[j] = &smem[4096 + cb * 512];
        }
    }

    const int fr = lane & 15;
    const int fk = (lane >> 4) * 8;

    auto stage = [&](int buf, int k0) {
        const int off = buf * 12288;
#pragma unroll
        for (int j = 0; j < 3; ++j) {
            gload16(gP[j] + k0,      lP[j] + off);
            gload16(gP[j] + k0 + 32, lP[j] + off + 6144);
        }
    };

    stage(0, 0);
    __syncthreads();
    int cur = 0;
    for (int k0 = 0; k0 < K; k0 += 64) {
        if (k0 + 64 < K) stage(cur ^ 1, k0 + 64);
        const int off = cur * 12288;
#pragma unroll
        for (int half = 0; half < 2; ++half) {
            const int base = off + half * 6144;
            bf16x8 af[2], bf[4];
#pragma unroll
            for (int mt = 0; mt < 2; ++mt)
                af[mt] = *(const bf16x8*)&smem[base + (w * 32 + mt * 16 + fr) * 32 + fk];
#pragma unroll
            for (int nt = 0; nt < 4; ++nt)
                bf[nt] = *(const bf16x8*)&smem[base + 4096 + (nt * 16 + fr) * 32 + fk];
#pragma unroll
            for (int mt = 0; mt < 2; ++mt)
#pragma unroll
                for (int nt = 0; nt < 4; ++nt)
                    acc[mt][nt] = __builtin_amdgcn_mfma_f32_16x16x32_bf16(
                        af[mt], bf[nt], acc[mt][nt], 0, 0, 0);
        }
        __syncthreads();
        cur ^= 1;
    }

#pragma unroll
    for (int mt = 0; mt < 2; ++mt) {
#pragma unroll
        for (int nt = 0; nt < 4; ++nt) {
            const int n = n0 + nt * 16 + fr;
            const float bias = bu[n];
#pragma unroll
            for (int r = 0; r < 4; ++r) {
                const int m = m0 + w * 32 + mt * 16 + (lane >> 4) * 4 + r;
                out[(size_t)m * E_ + n] = acc[mt][nt][r] + bias;
            }
        }
    }
}

// ---------------------------------------------------------------------------
// attention core (R6 version: XCD swizzle + early gather issue).
// ---------------------------------------------------------------------------
__global__ __launch_bounds__(256) void attn_kernel(
    const float* __restrict__ means, const float* __restrict__ sigmas,
    const float* __restrict__ values, const float* __restrict__ S,
    const uint16_t* __restrict__ Qt, const uint16_t* __restrict__ Kt,
    const uint16_t* __restrict__ Vt, uint16_t* __restrict__ united,
    float* __restrict__ attn)
{
    __shared__ float rowbuf[4][2048];
    const int w = threadIdx.x >> 6;
    const int lane = threadIdx.x & 63;
    const int bid = blockIdx.x;
    const int swz = (bid & 7) * 1024 + (bid >> 3);
    const int row = swz * 4 + w;
    const int bh = row >> 11;
    const int c = row & (C_ - 1);
    const int b = bh >> 3;
    const int h = bh & 7;

    const float* mrow = means + (size_t)row * 8;
    const float4 ma = *(const float4*)(mrow);
    const float4 mb = *(const float4*)(mrow + 4);
    const float mm[8] = {ma.x, ma.y, ma.z, ma.w, mb.x, mb.y, mb.z, mb.w};

    int idx[16];
#pragma unroll
    for (int j = 0; j < 8; ++j) {
        int i0 = (int)floorf(mm[j]);
        i0 = min(max(i0, 0), C_ - 1);
        idx[2 * j] = i0;
        idx[2 * j + 1] = min(i0 + 1, C_ - 1);
    }

    // ---- (p,g) layout: p = point (lane>>2), g = quarter (lane&3) ----
    const int p = lane >> 2, g = lane & 3;
    int kidx = 0;
#pragma unroll
    for (int q = 0; q < 16; ++q)
        if (q == p) kidx = idx[q];

    // ---- EARLY ISSUE: all global gathers, addresses depend only on idx ----
    const uint16_t* Qrow = Qt + ((size_t)row << 6);
    const uint16_t* Krow = Kt + ((((size_t)bh << 11) + kidx) << 6);
    const u16x8 qa = *(const u16x8*)(Qrow + g * 16);
    const u16x8 qb = *(const u16x8*)(Qrow + g * 16 + 8);
    const u16x8 ka = *(const u16x8*)(Krow + g * 16);
    const u16x8 kb = *(const u16x8*)(Krow + g * 16 + 8);
    const uint16_t* Vbh = Vt + ((size_t)bh << 17);
    uint16_t vv[16];
#pragma unroll
    for (int q = 0; q < 16; ++q)
        vv[q] = Vbh[((size_t)idx[q] << 6) + lane];

    // duplicate-point check for own p (wave-uniform idx[] in registers)
    bool dup = false;
#pragma unroll
    for (int q = 0; q < 15; ++q)
        dup = dup || ((q < p) && (idx[q] == kidx));

    // ---- per-point weight, parallel over (p, kk): lane handles kk=g,g+4 ----
    float mA = 0.f, mB = 0.f;
#pragma unroll
    for (int q = 0; q < 4; ++q)
        if (q == g) { mA = mm[q]; mB = mm[q + 4]; }
    const float* srow = sigmas + (size_t)row * 8;
    const float* vrow = values + (size_t)row * 8;
    const float* Sp = S + bh * 128 + p * 8;
    const float sgA = srow[g], sgB = srow[g + 4];
    const float vlA = vrow[g], vlB = vrow[g + 4];
    const float SvA = Sp[g],   SvB = Sp[g + 4];
    const float fi = (float)kidx;
    const float tA = (fi - mA) / sgA;
    const float tB = (fi - mB) / sgB;
    const float eA = expf(-0.5f * tA * tA);
    const float eB = expf(-0.5f * tB * tB);
    float wp = dup ? 0.0f
                   : fmaf(vlA, eA / (SvA + 1e-8f), vlB * eB / (SvB + 1e-8f));
    wp += __shfl_xor(wp, 1);
    wp += __shfl_xor(wp, 2);          // wp == wvp, replicated in 4-lane group

    // ---- Q.K dot: lane covers dims [g*16, g*16+16) of point p ----
    float dot = 0.0f;
#pragma unroll
    for (int j = 0; j < 8; ++j) {
        dot = fmaf(bf2f(qa[j]), bf2f(ka[j]), dot);
        dot = fmaf(bf2f(qb[j]), bf2f(kb[j]), dot);
    }
    dot += __shfl_xor(dot, 1);
    dot += __shfl_xor(dot, 2);

    const float logit = wp * dot;

    float mx = logit;
#pragma unroll
    for (int off = 4; off < 64; off <<= 1)
        mx = fmaxf(mx, __shfl_xor(mx, off));
    const float e = expf(logit - mx);
    float se = e;
#pragma unroll
    for (int off = 4; off < 64; off <<= 1)
        se += __shfl_xor(se, off);
    const float sm = e / se;

    float smv[16];
#pragma unroll
    for (int q = 0; q < 16; ++q)
        smv[q] = __shfl(sm, q * 4);

    // ---- V combine (lane = d) with preloaded vv ----
    float acc = 0.0f;
#pragma unroll
    for (int q = 0; q < 16; ++q)
        acc = fmaf(bf2f(vv[q]), smv[q], acc);
    united[((size_t)(b * C_ + c)) * HD_ + h * 64 + lane] = f2bf(acc);

    // ---- attentions row: zero LDS, scatter-add, nontemporal stream out ----
    const f32x4 z4 = {0.f, 0.f, 0.f, 0.f};
#pragma unroll
    for (int j = 0; j < 8; ++j)
        *(f32x4*)&rowbuf[w][(j * 64 + lane) * 4] = z4;
    __syncthreads();
    if (g == 0) atomicAdd(&rowbuf[w][kidx], sm);   // one lane per point p
    __syncthreads();
    float* arow = attn + ((size_t)row << 11);
#pragma unroll
    for (int j = 0; j < 8; ++j) {
        const int o = (j * 64 + lane) * 4;
        __builtin_nontemporal_store(*(const f32x4*)&rowbuf[w][o], (f32x4*)&arow[o]);
    }
}

// ---------------------------------------------------------------------------
// DIAGNOSTIC ROUND: the pipeline is launched TWICE (idempotent end-to-end —
// S is re-zeroed before each prep; all other buffers are pure overwrites
// with identical values).  Delta vs R6's 379.6 µs = T_pipeline, splitting
// wall time into {our kernels} vs {fixed in-window overhead}.
// ---------------------------------------------------------------------------
extern "C" void kernel_launch(void* const* d_in, const int* in_sizes, int n_in,
                              void* d_out, int out_size, void* d_ws,
                              size_t ws_size, hipStream_t stream) {
    const float* x      = (const float*)d_in[0];
    const float* means  = (const float*)d_in[2];
    const float* sigmas = (const float*)d_in[3];
    const float* values = (const float*)d_in[4];
    const float* Wk     = (const float*)d_in[5];
    const float* Wq     = (const float*)d_in[6];
    const float* Wv     = (const float*)d_in[7];
    const float* Wu     = (const float*)d_in[8];
    const float* bu     = (const float*)d_in[9];

    float* out  = (float*)d_out;
    float* attn = out + (size_t)M_ * E_;

    uint16_t* wsp = (uint16_t*)d_ws;
    uint16_t* xb     = wsp;                              // 4194304
    uint16_t* Wall   = xb + 4194304;                     // 1572864 (1536x1024)
    uint16_t* Wut    = Wall + 1572864;                   // 524288
    uint16_t* Qt     = Wut + 524288;                     // 2097152
    uint16_t* Kt     = Qt + 2097152;
    uint16_t* Vt     = Kt + 2097152;
    uint16_t* united = Vt + 2097152;                     // 2097152
    float*    S      = (float*)(united + 2097152);       // 2048 floats

    for (int rep = 0; rep < 2; ++rep) {
        (void)hipMemsetAsync(S, 0, 2048 * sizeof(float), stream);
        prep_kernel<<<4224, 256, 0, stream>>>(
            x, Wq, Wk, Wv, Wu, means, sigmas, xb, Wall, Wut, S);
        gemm_qkv_kernel<<<dim3(24, 32), 256, 0, stream>>>(xb, Wall, Qt, Kt, Vt);
        attn_kernel<<<ROWS_ / 4, 256, 0, stream>>>(
            means, sigmas, values, S, Qt, Kt, Vt, united, attn);
        gemm_out_kernel<<<dim3(16, 32), 256, 0, stream>>>(united, Wut, bu, out);
    }
}

// Round 8
// 385.381 us; speedup vs baseline: 1.2865x; 1.2865x over previous
//
#include <hip/hip_runtime.h>
#include <math.h>
#include <stdint.h>

#define B_ 2
#define H_ 8
#define C_ 2048
#define E_ 1024
#define D_ 64
#define KP_ 8
#define P_ 16
#define HD_ 512              // H*D
#define ROWS_ 32768          // B*H*C
#define M_ 4096              // B*C

typedef __bf16 bf16x8 __attribute__((ext_vector_type(8)));
typedef float f32x4 __attribute__((ext_vector_type(4)));
typedef uint16_t u16x8 __attribute__((ext_vector_type(8)));

__device__ inline uint16_t f2bf(float f) {
    union { float f; uint32_t u; } v; v.f = f;
    uint32_t u = v.u + 0x7FFF + ((v.u >> 16) & 1);   // RNE
    return (uint16_t)(u >> 16);
}
__device__ inline float bf2f(uint16_t h) {
    union { uint32_t u; float f; } v; v.u = ((uint32_t)h) << 16;
    return v.f;
}

// async global->LDS, 16B per lane; LDS dest = wave-uniform base + lane*16
__device__ inline void gload16(const uint16_t* g, uint16_t* l) {
    __builtin_amdgcn_global_load_lds(
        (const __attribute__((address_space(1))) void*)g,
        (__attribute__((address_space(3))) void*)l, 16, 0, 0);
}

// ---------------------------------------------------------------------------
// prep kernel: x-convert, weight transpose-convert, density context-sums.
// (measured ~at traffic floor; unchanged)
// ---------------------------------------------------------------------------
__global__ __launch_bounds__(256) void prep_kernel(
    const float* __restrict__ x,
    const float* __restrict__ Wq, const float* __restrict__ Wk,
    const float* __restrict__ Wv, const float* __restrict__ Wu,
    const float* __restrict__ means, const float* __restrict__ sigmas,
    uint16_t* __restrict__ xb, uint16_t* __restrict__ Wall,
    uint16_t* __restrict__ Wut, float* __restrict__ S)
{
    const int bx = blockIdx.x;
    if (bx < 2048) {
        const int i = (bx * 256 + threadIdx.x) * 8;
        const float4 a = *(const float4*)(x + i);
        const float4 b = *(const float4*)(x + i + 4);
        u16x8 o;
        o[0] = f2bf(a.x); o[1] = f2bf(a.y); o[2] = f2bf(a.z); o[3] = f2bf(a.w);
        o[4] = f2bf(b.x); o[5] = f2bf(b.y); o[6] = f2bf(b.z); o[7] = f2bf(b.w);
        *(u16x8*)(xb + i) = o;
        return;
    }
    if (bx < 4096) {
        const int t = bx - 2048;
        const int z = t >> 9;
        const float* in; uint16_t* out; int R, Cc; float scale;
        if (z == 0)      { in = Wq; out = Wall;               R = E_;  Cc = HD_; scale = 0.125f; }
        else if (z == 1) { in = Wk; out = Wall + 512 * 1024;  R = E_;  Cc = HD_; scale = 0.125f; }
        else if (z == 2) { in = Wv; out = Wall + 1024 * 1024; R = E_;  Cc = HD_; scale = 1.0f; }
        else             { in = Wu; out = Wut;                R = HD_; Cc = E_;  scale = 1.0f; }
        const int tiles_x = Cc >> 5;
        const int ti = t & 511;
        const int tx = ti % tiles_x;
        const int ty = ti / tiles_x;
        const int r0 = ty * 32, c0 = tx * 32;
        __shared__ float tbuf[32][33];
        const int lx = threadIdx.x & 31, ly = threadIdx.x >> 5;
#pragma unroll
        for (int i = 0; i < 4; ++i)
            tbuf[ly * 4 + i][lx] = in[(size_t)(r0 + ly * 4 + i) * Cc + c0 + lx];
        __syncthreads();
#pragma unroll
        for (int i = 0; i < 4; ++i)
            out[(size_t)(c0 + ly * 4 + i) * R + r0 + lx] =
                f2bf(tbuf[lx][ly * 4 + i] * scale);
        return;
    }
    // ---- density sums ----
    const int row = (bx - 4096) * 256 + threadIdx.x;
    const int lane = threadIdx.x & 63;
    const int bh = row >> 11;          // constant per block (256 rows/block)

    __shared__ float Sacc[128];
    if (threadIdx.x < 128) Sacc[threadIdx.x] = 0.0f;
    __syncthreads();

    const float* mrow = means + (size_t)row * 8;
    const float* srow = sigmas + (size_t)row * 8;
    const float4 ma = *(const float4*)(mrow);
    const float4 mb = *(const float4*)(mrow + 4);
    const float4 sa = *(const float4*)(srow);
    const float4 sb = *(const float4*)(srow + 4);
    const float mm[8] = {ma.x, ma.y, ma.z, ma.w, mb.x, mb.y, mb.z, mb.w};
    const float sg[8] = {sa.x, sa.y, sa.z, sa.w, sb.x, sb.y, sb.z, sb.w};

    int idx[16];
#pragma unroll
    for (int j = 0; j < 8; ++j) {
        int i0 = (int)floorf(mm[j]);
        i0 = min(max(i0, 0), C_ - 1);
        idx[2 * j] = i0;
        idx[2 * j + 1] = min(i0 + 1, C_ - 1);
    }
    unsigned dupm = 0;
#pragma unroll
    for (int p = 1; p < 16; ++p) {
        bool d = false;
#pragma unroll
        for (int q = 0; q < 15; ++q)
            if (q < p) d = d || (idx[q] == idx[p]);
        if (d) dupm |= (1u << p);
    }

    // lane's final slot after the 6-stage butterfly is bitrev6(lane)
    const int rev = ((lane & 1) << 5) | ((lane & 2) << 3) | ((lane & 4) << 1) |
                    ((lane & 8) >> 1) | ((lane & 16) >> 3) | ((lane & 32) >> 5);

#pragma unroll
    for (int ph = 0; ph < 2; ++ph) {
        float a[64];
#pragma unroll
        for (int j = 0; j < 64; ++j) {
            const int p = ph * 8 + (j >> 3);
            const int kk = j & 7;
            const float fi = (float)idx[p];
            const float t = (fi - mm[kk]) / sg[kk];
            const float e = expf(-0.5f * t * t);
            a[j] = ((dupm >> p) & 1u) ? 0.0f : e;
        }
        // recursive halving butterfly reduce
#pragma unroll
        for (int b = 0; b < 6; ++b) {
            const int n = 32 >> b;
            const bool hi = (lane >> b) & 1;
#pragma unroll
            for (int j = 0; j < n; ++j) {
                float send = hi ? a[j] : a[j + n];
                float recv = __shfl_xor(send, 1 << b);
                a[j] = (hi ? a[j + n] : a[j]) + recv;
            }
        }
        atomicAdd(&Sacc[ph * 64 + rev], a[0]);
    }
    __syncthreads();
    if (threadIdx.x < 128)
        atomicAdd(&S[bh * 128 + threadIdx.x], Sacc[threadIdx.x]);
}

// ---------------------------------------------------------------------------
// Fused QKV GEMM, m97-style 128x128 tile: 4 waves in 64x64 quadrants,
// acc[4][4]/wave, BK=32 double-buffered -> 16 MFMA per 8 ds_read_b128
// (2x the MFMA/byte of the old 128x64 tile).  12x32 = 384 blocks.
// Epilogue: stride-144 LDS stage (conflict-free), tile spans 2 heads.
// ---------------------------------------------------------------------------
__global__ __launch_bounds__(256) void gemm_qkv_kernel(
    const uint16_t* __restrict__ xb, const uint16_t* __restrict__ Wall,
    uint16_t* __restrict__ Qt, uint16_t* __restrict__ Kt,
    uint16_t* __restrict__ Vt)
{
    const int K = E_;                       // 1024
    const int m0 = blockIdx.y * 128;
    const int n0 = blockIdx.x * 128;        // 0..1408; never spans Q/K/V bounds
    const int z = n0 >> 9;
    uint16_t* __restrict__ Out = (z == 0) ? Qt : (z == 1) ? Kt : Vt;
    const int hb = (n0 & 511) >> 6;         // first head of the 2 in this tile

    // K-loop: 2 bufs x (A 4096 + B 4096) u16 = 32 KB; epilogue 128x144 = 36 KB
    __shared__ __align__(16) uint16_t smem[18432];

    const int tid = threadIdx.x;
    const int w = tid >> 6, lane = tid & 63;
    const int qr = w >> 1, qc = w & 1;      // wave quadrant

    f32x4 acc[4][4] = {};

    // staging: 16 chunks of 16 rows x 32 k-cols (A 0-7, B 8-15); wave w: 4w..4w+3
    const uint16_t* gP[4];
    uint16_t* lP[4];
#pragma unroll
    for (int j = 0; j < 4; ++j) {
        const int ci = w * 4 + j;
        const int rr = (ci & 7) * 16 + (lane >> 2);
        const int ko = (lane & 3) * 8;
        if (ci < 8) {
            gP[j] = xb + (size_t)(m0 + rr) * K + ko;
            lP[j] = &smem[ci * 512];
        } else {
            gP[j] = Wall + (size_t)(n0 + rr) * K + ko;
            lP[j] = &smem[4096 + (ci - 8) * 512];
        }
    }

    const int fr = lane & 15;
    const int fk = (lane >> 4) * 8;

    auto stage = [&](int buf, int k0) {
        const int off = buf * 8192;
#pragma unroll
        for (int j = 0; j < 4; ++j)
            gload16(gP[j] + k0, lP[j] + off);
    };

    stage(0, 0);
    __syncthreads();                         // drain prologue loads
    int cur = 0;
    for (int k0 = 0; k0 < K; k0 += 32) {
        if (k0 + 32 < K) stage(cur ^ 1, k0 + 32);
        const int off = cur * 8192;
        bf16x8 af[4], bf[4];
#pragma unroll
        for (int mt = 0; mt < 4; ++mt)
            af[mt] = *(const bf16x8*)&smem[off + (qr * 64 + mt * 16 + fr) * 32 + fk];
#pragma unroll
        for (int nt = 0; nt < 4; ++nt)
            bf[nt] = *(const bf16x8*)&smem[off + 4096 + (qc * 64 + nt * 16 + fr) * 32 + fk];
#pragma unroll
        for (int mt = 0; mt < 4; ++mt)
#pragma unroll
            for (int nt = 0; nt < 4; ++nt)
                acc[mt][nt] = __builtin_amdgcn_mfma_f32_16x16x32_bf16(
                    af[mt], bf[nt], acc[mt][nt], 0, 0, 0);
        __syncthreads();   // drains prefetch vmcnt + all waves' ds_reads
        cur ^= 1;
    }

    // ---- epilogue: stage 128x128 bf16 (stride 144: banks conflict-free) ----
#pragma unroll
    for (int mt = 0; mt < 4; ++mt)
#pragma unroll
        for (int nt = 0; nt < 4; ++nt) {
            const int col = qc * 64 + nt * 16 + fr;
#pragma unroll
            for (int r = 0; r < 4; ++r) {
                const int rw = qr * 64 + mt * 16 + (lane >> 4) * 4 + r;
                smem[rw * 144 + col] = f2bf(acc[mt][nt][r]);
            }
        }
    __syncthreads();
#pragma unroll
    for (int it = 0; it < 8; ++it) {
        const int j = it * 256 + tid;       // 0..2047 chunks of 8
        const int row = j >> 4, c8 = (j & 15) * 8;
        const int m = m0 + row;
        const int b = m >> 11, c = m & (C_ - 1);
        const int h = hb + (c8 >> 6);
        *(u16x8*)&Out[(((size_t)(b * H_ + h) * C_ + c) << 6) + (c8 & 63)] =
            *(const u16x8*)&smem[row * 144 + c8];
    }
}

// ---------------------------------------------------------------------------
// GEMM 2, 128x128 tile (same structure), 8x32 = 256 blocks, K=512.
// united (4096x512) @ Wu^T-rows (1024x512) + bu -> new_out fp32
// ---------------------------------------------------------------------------
__global__ __launch_bounds__(256) void gemm_out_kernel(
    const uint16_t* __restrict__ U, const uint16_t* __restrict__ Wut,
    const float* __restrict__ bu, float* __restrict__ out)
{
    const int K = HD_;                      // 512
    const int m0 = blockIdx.y * 128;
    const int n0 = blockIdx.x * 128;        // N=1024

    __shared__ __align__(16) uint16_t smem[16384];   // 2 bufs x 16 KB

    const int tid = threadIdx.x;
    const int w = tid >> 6, lane = tid & 63;
    const int qr = w >> 1, qc = w & 1;

    f32x4 acc[4][4] = {};

    const uint16_t* gP[4];
    uint16_t* lP[4];
#pragma unroll
    for (int j = 0; j < 4; ++j) {
        const int ci = w * 4 + j;
        const int rr = (ci & 7) * 16 + (lane >> 2);
        const int ko = (lane & 3) * 8;
        if (ci < 8) {
            gP[j] = U + (size_t)(m0 + rr) * K + ko;
            lP[j] = &smem[ci * 512];
        } else {
            gP[j] = Wut + (size_t)(n0 + rr) * K + ko;
            lP[j] = &smem[4096 + (ci - 8) * 512];
        }
    }

    const int fr = lane & 15;
    const int fk = (lane >> 4) * 8;

    auto stage = [&](int buf, int k0) {
        const int off = buf * 8192;
#pragma unroll
        for (int j = 0; j < 4; ++j)
            gload16(gP[j] + k0, lP[j] + off);
    };

    stage(0, 0);
    __syncthreads();
    int cur = 0;
    for (int k0 = 0; k0 < K; k0 += 32) {
        if (k0 + 32 < K) stage(cur ^ 1, k0 + 32);
        const int off = cur * 8192;
        bf16x8 af[4], bf[4];
#pragma unroll
        for (int mt = 0; mt < 4; ++mt)
            af[mt] = *(const bf16x8*)&smem[off + (qr * 64 + mt * 16 + fr) * 32 + fk];
#pragma unroll
        for (int nt = 0; nt < 4; ++nt)
            bf[nt] = *(const bf16x8*)&smem[off + 4096 + (qc * 64 + nt * 16 + fr) * 32 + fk];
#pragma unroll
        for (int mt = 0; mt < 4; ++mt)
#pragma unroll
            for (int nt = 0; nt < 4; ++nt)
                acc[mt][nt] = __builtin_amdgcn_mfma_f32_16x16x32_bf16(
                    af[mt], bf[nt], acc[mt][nt], 0, 0, 0);
        __syncthreads();
        cur ^= 1;
    }

#pragma unroll
    for (int mt = 0; mt < 4; ++mt) {
#pragma unroll
        for (int nt = 0; nt < 4; ++nt) {
            const int n = n0 + qc * 64 + nt * 16 + fr;
            const float bias = bu[n];
#pragma unroll
            for (int r = 0; r < 4; ++r) {
                const int m = m0 + qr * 64 + mt * 16 + (lane >> 4) * 4 + r;
                out[(size_t)m * E_ + n] = acc[mt][nt][r] + bias;
            }
        }
    }
}

// ---------------------------------------------------------------------------
// attention core (R6 version: XCD swizzle + early gather issue; near the
// 268 MB dense-write floor).
// ---------------------------------------------------------------------------
__global__ __launch_bounds__(256) void attn_kernel(
    const float* __restrict__ means, const float* __restrict__ sigmas,
    const float* __restrict__ values, const float* __restrict__ S,
    const uint16_t* __restrict__ Qt, const uint16_t* __restrict__ Kt,
    const uint16_t* __restrict__ Vt, uint16_t* __restrict__ united,
    float* __restrict__ attn)
{
    __shared__ float rowbuf[4][2048];
    const int w = threadIdx.x >> 6;
    const int lane = threadIdx.x & 63;
    const int bid = blockIdx.x;
    const int swz = (bid & 7) * 1024 + (bid >> 3);
    const int row = swz * 4 + w;
    const int bh = row >> 11;
    const int c = row & (C_ - 1);
    const int b = bh >> 3;
    const int h = bh & 7;

    const float* mrow = means + (size_t)row * 8;
    const float4 ma = *(const float4*)(mrow);
    const float4 mb = *(const float4*)(mrow + 4);
    const float mm[8] = {ma.x, ma.y, ma.z, ma.w, mb.x, mb.y, mb.z, mb.w};

    int idx[16];
#pragma unroll
    for (int j = 0; j < 8; ++j) {
        int i0 = (int)floorf(mm[j]);
        i0 = min(max(i0, 0), C_ - 1);
        idx[2 * j] = i0;
        idx[2 * j + 1] = min(i0 + 1, C_ - 1);
    }

    // ---- (p,g) layout: p = point (lane>>2), g = quarter (lane&3) ----
    const int p = lane >> 2, g = lane & 3;
    int kidx = 0;
#pragma unroll
    for (int q = 0; q < 16; ++q)
        if (q == p) kidx = idx[q];

    // ---- EARLY ISSUE: all global gathers, addresses depend only on idx ----
    const uint16_t* Qrow = Qt + ((size_t)row << 6);
    const uint16_t* Krow = Kt + ((((size_t)bh << 11) + kidx) << 6);
    const u16x8 qa = *(const u16x8*)(Qrow + g * 16);
    const u16x8 qb = *(const u16x8*)(Qrow + g * 16 + 8);
    const u16x8 ka = *(const u16x8*)(Krow + g * 16);
    const u16x8 kb = *(const u16x8*)(Krow + g * 16 + 8);
    const uint16_t* Vbh = Vt + ((size_t)bh << 17);
    uint16_t vv[16];
#pragma unroll
    for (int q = 0; q < 16; ++q)
        vv[q] = Vbh[((size_t)idx[q] << 6) + lane];

    // duplicate-point check for own p (wave-uniform idx[] in registers)
    bool dup = false;
#pragma unroll
    for (int q = 0; q < 15; ++q)
        dup = dup || ((q < p) && (idx[q] == kidx));

    // ---- per-point weight, parallel over (p, kk): lane handles kk=g,g+4 ----
    float mA = 0.f, mB = 0.f;
#pragma unroll
    for (int q = 0; q < 4; ++q)
        if (q == g) { mA = mm[q]; mB = mm[q + 4]; }
    const float* srow = sigmas + (size_t)row * 8;
    const float* vrow = values + (size_t)row * 8;
    const float* Sp = S + bh * 128 + p * 8;
    const float sgA = srow[g], sgB = srow[g + 4];
    const float vlA = vrow[g], vlB = vrow[g + 4];
    const float SvA = Sp[g],   SvB = Sp[g + 4];
    const float fi = (float)kidx;
    const float tA = (fi - mA) / sgA;
    const float tB = (fi - mB) / sgB;
    const float eA = expf(-0.5f * tA * tA);
    const float eB = expf(-0.5f * tB * tB);
    float wp = dup ? 0.0f
                   : fmaf(vlA, eA / (SvA + 1e-8f), vlB * eB / (SvB + 1e-8f));
    wp += __shfl_xor(wp, 1);
    wp += __shfl_xor(wp, 2);          // wp == wvp, replicated in 4-lane group

    // ---- Q.K dot: lane covers dims [g*16, g*16+16) of point p ----
    float dot = 0.0f;
#pragma unroll
    for (int j = 0; j < 8; ++j) {
        dot = fmaf(bf2f(qa[j]), bf2f(ka[j]), dot);
        dot = fmaf(bf2f(qb[j]), bf2f(kb[j]), dot);
    }
    dot += __shfl_xor(dot, 1);
    dot += __shfl_xor(dot, 2);

    const float logit = wp * dot;

    float mx = logit;
#pragma unroll
    for (int off = 4; off < 64; off <<= 1)
        mx = fmaxf(mx, __shfl_xor(mx, off));
    const float e = expf(logit - mx);
    float se = e;
#pragma unroll
    for (int off = 4; off < 64; off <<= 1)
        se += __shfl_xor(se, off);
    const float sm = e / se;

    float smv[16];
#pragma unroll
    for (int q = 0; q < 16; ++q)
        smv[q] = __shfl(sm, q * 4);

    // ---- V combine (lane = d) with preloaded vv ----
    float acc = 0.0f;
#pragma unroll
    for (int q = 0; q < 16; ++q)
        acc = fmaf(bf2f(vv[q]), smv[q], acc);
    united[((size_t)(b * C_ + c)) * HD_ + h * 64 + lane] = f2bf(acc);

    // ---- attentions row: zero LDS, scatter-add, nontemporal stream out ----
    const f32x4 z4 = {0.f, 0.f, 0.f, 0.f};
#pragma unroll
    for (int j = 0; j < 8; ++j)
        *(f32x4*)&rowbuf[w][(j * 64 + lane) * 4] = z4;
    __syncthreads();
    if (g == 0) atomicAdd(&rowbuf[w][kidx], sm);   // one lane per point p
    __syncthreads();
    float* arow = attn + ((size_t)row << 11);
#pragma unroll
    for (int j = 0; j < 8; ++j) {
        const int o = (j * 64 + lane) * 4;
        __builtin_nontemporal_store(*(const f32x4*)&rowbuf[w][o], (f32x4*)&arow[o]);
    }
}

// ---------------------------------------------------------------------------
// R7 duplication experiment: T_pipeline(warm) = 116 us; fixed in-window
// harness overhead ~= 250-265 us (1.14 GB poison fill @ 175 us + resets).
// Single pipeline restored.
// ---------------------------------------------------------------------------
extern "C" void kernel_launch(void* const* d_in, const int* in_sizes, int n_in,
                              void* d_out, int out_size, void* d_ws,
                              size_t ws_size, hipStream_t stream) {
    const float* x      = (const float*)d_in[0];
    const float* means  = (const float*)d_in[2];
    const float* sigmas = (const float*)d_in[3];
    const float* values = (const float*)d_in[4];
    const float* Wk     = (const float*)d_in[5];
    const float* Wq     = (const float*)d_in[6];
    const float* Wv     = (const float*)d_in[7];
    const float* Wu     = (const float*)d_in[8];
    const float* bu     = (const float*)d_in[9];

    float* out  = (float*)d_out;
    float* attn = out + (size_t)M_ * E_;

    uint16_t* wsp = (uint16_t*)d_ws;
    uint16_t* xb     = wsp;                              // 4194304
    uint16_t* Wall   = xb + 4194304;                     // 1572864 (1536x1024)
    uint16_t* Wut    = Wall + 1572864;                   // 524288
    uint16_t* Qt     = Wut + 524288;                     // 2097152
    uint16_t* Kt     = Qt + 2097152;
    uint16_t* Vt     = Kt + 2097152;
    uint16_t* united = Vt + 2097152;                     // 2097152
    float*    S      = (float*)(united + 2097152);       // 2048 floats

    (void)hipMemsetAsync(S, 0, 2048 * sizeof(float), stream);

    prep_kernel<<<4224, 256, 0, stream>>>(
        x, Wq, Wk, Wv, Wu, means, sigmas, xb, Wall, Wut, S);
    gemm_qkv_kernel<<<dim3(12, 32), 256, 0, stream>>>(xb, Wall, Qt, Kt, Vt);
    attn_kernel<<<ROWS_ / 4, 256, 0, stream>>>(
        means, sigmas, values, S, Qt, Kt, Vt, united, attn);
    gemm_out_kernel<<<dim3(8, 32), 256, 0, stream>>>(united, Wut, bu, out);
}

// Round 9
// 379.304 us; speedup vs baseline: 1.3071x; 1.0160x over previous
//
#include <hip/hip_runtime.h>
#include <math.h>
#include <stdint.h>

#define B_ 2
#define H_ 8
#define C_ 2048
#define E_ 1024
#define D_ 64
#define KP_ 8
#define P_ 16
#define HD_ 512              // H*D
#define ROWS_ 32768          // B*H*C
#define M_ 4096              // B*C

typedef __bf16 bf16x8 __attribute__((ext_vector_type(8)));
typedef float f32x4 __attribute__((ext_vector_type(4)));
typedef uint16_t u16x8 __attribute__((ext_vector_type(8)));

__device__ inline uint16_t f2bf(float f) {
    union { float f; uint32_t u; } v; v.f = f;
    uint32_t u = v.u + 0x7FFF + ((v.u >> 16) & 1);   // RNE
    return (uint16_t)(u >> 16);
}
__device__ inline float bf2f(uint16_t h) {
    union { uint32_t u; float f; } v; v.u = ((uint32_t)h) << 16;
    return v.f;
}

// async global->LDS, 16B per lane; LDS dest = wave-uniform base + lane*16
__device__ inline void gload16(const uint16_t* g, uint16_t* l) {
    __builtin_amdgcn_global_load_lds(
        (const __attribute__((address_space(1))) void*)g,
        (__attribute__((address_space(3))) void*)l, 16, 0, 0);
}

// ---------------------------------------------------------------------------
// prep kernel: x-convert, weight transpose-convert, density context-sums.
// ---------------------------------------------------------------------------
__global__ __launch_bounds__(256) void prep_kernel(
    const float* __restrict__ x,
    const float* __restrict__ Wq, const float* __restrict__ Wk,
    const float* __restrict__ Wv, const float* __restrict__ Wu,
    const float* __restrict__ means, const float* __restrict__ sigmas,
    uint16_t* __restrict__ xb, uint16_t* __restrict__ Wall,
    uint16_t* __restrict__ Wut, float* __restrict__ S)
{
    const int bx = blockIdx.x;
    if (bx < 2048) {
        const int i = (bx * 256 + threadIdx.x) * 8;
        const float4 a = *(const float4*)(x + i);
        const float4 b = *(const float4*)(x + i + 4);
        u16x8 o;
        o[0] = f2bf(a.x); o[1] = f2bf(a.y); o[2] = f2bf(a.z); o[3] = f2bf(a.w);
        o[4] = f2bf(b.x); o[5] = f2bf(b.y); o[6] = f2bf(b.z); o[7] = f2bf(b.w);
        *(u16x8*)(xb + i) = o;
        return;
    }
    if (bx < 4096) {
        const int t = bx - 2048;
        const int z = t >> 9;
        const float* in; uint16_t* out; int R, Cc; float scale;
        if (z == 0)      { in = Wq; out = Wall;               R = E_;  Cc = HD_; scale = 0.125f; }
        else if (z == 1) { in = Wk; out = Wall + 512 * 1024;  R = E_;  Cc = HD_; scale = 0.125f; }
        else if (z == 2) { in = Wv; out = Wall + 1024 * 1024; R = E_;  Cc = HD_; scale = 1.0f; }
        else             { in = Wu; out = Wut;                R = HD_; Cc = E_;  scale = 1.0f; }
        const int tiles_x = Cc >> 5;
        const int ti = t & 511;
        const int tx = ti % tiles_x;
        const int ty = ti / tiles_x;
        const int r0 = ty * 32, c0 = tx * 32;
        __shared__ float tbuf[32][33];
        const int lx = threadIdx.x & 31, ly = threadIdx.x >> 5;
#pragma unroll
        for (int i = 0; i < 4; ++i)
            tbuf[ly * 4 + i][lx] = in[(size_t)(r0 + ly * 4 + i) * Cc + c0 + lx];
        __syncthreads();
#pragma unroll
        for (int i = 0; i < 4; ++i)
            out[(size_t)(c0 + ly * 4 + i) * R + r0 + lx] =
                f2bf(tbuf[lx][ly * 4 + i] * scale);
        return;
    }
    // ---- density sums ----
    const int row = (bx - 4096) * 256 + threadIdx.x;
    const int lane = threadIdx.x & 63;
    const int bh = row >> 11;          // constant per block (256 rows/block)

    __shared__ float Sacc[128];
    if (threadIdx.x < 128) Sacc[threadIdx.x] = 0.0f;
    __syncthreads();

    const float* mrow = means + (size_t)row * 8;
    const float* srow = sigmas + (size_t)row * 8;
    const float4 ma = *(const float4*)(mrow);
    const float4 mb = *(const float4*)(mrow + 4);
    const float4 sa = *(const float4*)(srow);
    const float4 sb = *(const float4*)(srow + 4);
    const float mm[8] = {ma.x, ma.y, ma.z, ma.w, mb.x, mb.y, mb.z, mb.w};
    const float sg[8] = {sa.x, sa.y, sa.z, sa.w, sb.x, sb.y, sb.z, sb.w};

    int idx[16];
#pragma unroll
    for (int j = 0; j < 8; ++j) {
        int i0 = (int)floorf(mm[j]);
        i0 = min(max(i0, 0), C_ - 1);
        idx[2 * j] = i0;
        idx[2 * j + 1] = min(i0 + 1, C_ - 1);
    }
    unsigned dupm = 0;
#pragma unroll
    for (int p = 1; p < 16; ++p) {
        bool d = false;
#pragma unroll
        for (int q = 0; q < 15; ++q)
            if (q < p) d = d || (idx[q] == idx[p]);
        if (d) dupm |= (1u << p);
    }

    // lane's final slot after the 6-stage butterfly is bitrev6(lane)
    const int rev = ((lane & 1) << 5) | ((lane & 2) << 3) | ((lane & 4) << 1) |
                    ((lane & 8) >> 1) | ((lane & 16) >> 3) | ((lane & 32) >> 5);

#pragma unroll
    for (int ph = 0; ph < 2; ++ph) {
        float a[64];
#pragma unroll
        for (int j = 0; j < 64; ++j) {
            const int p = ph * 8 + (j >> 3);
            const int kk = j & 7;
            const float fi = (float)idx[p];
            const float t = (fi - mm[kk]) / sg[kk];
            const float e = expf(-0.5f * t * t);
            a[j] = ((dupm >> p) & 1u) ? 0.0f : e;
        }
        // recursive halving butterfly reduce
#pragma unroll
        for (int b = 0; b < 6; ++b) {
            const int n = 32 >> b;
            const bool hi = (lane >> b) & 1;
#pragma unroll
            for (int j = 0; j < n; ++j) {
                float send = hi ? a[j] : a[j + n];
                float recv = __shfl_xor(send, 1 << b);
                a[j] = (hi ? a[j + n] : a[j]) + recv;
            }
        }
        atomicAdd(&Sacc[ph * 64 + rev], a[0]);
    }
    __syncthreads();
    if (threadIdx.x < 128)
        atomicAdd(&S[bh * 128 + threadIdx.x], Sacc[threadIdx.x]);
}

// ---------------------------------------------------------------------------
// Fused QKV GEMM (MFMA bf16), 128x64 tiles, BK=64, double-buffered prefetch.
// 768 blocks = 3.0/CU (R8 showed 128x128 tiles regress: grid 1.5/CU starves
// TLP at these narrow N; this config is the measured optimum).
// ---------------------------------------------------------------------------
__global__ __launch_bounds__(256) void gemm_qkv_kernel(
    const uint16_t* __restrict__ xb, const uint16_t* __restrict__ Wall,
    uint16_t* __restrict__ Qt, uint16_t* __restrict__ Kt,
    uint16_t* __restrict__ Vt)
{
    const int K = E_;                       // 1024
    const int m0 = blockIdx.y * 128;
    const int n0 = blockIdx.x * 64;         // 0..1535
    const int z = n0 >> 9;
    uint16_t* __restrict__ Out = (z == 0) ? Qt : (z == 1) ? Kt : Vt;
    const int h = (n0 & 511) >> 6;          // single head per block

    __shared__ __align__(16) uint16_t smem[24576];   // 48 KB, 3 blocks/CU

    const int tid = threadIdx.x;
    const int w = tid >> 6, lane = tid & 63;

    f32x4 acc[2][4] = {};

    const uint16_t* gP[3];
    uint16_t* lP[3];
#pragma unroll
    for (int j = 0; j < 3; ++j) {
        const int ci = w * 3 + j;
        const int rr = (ci & 7) * 16 + (lane >> 2);   // works for both halves
        const int ko = (lane & 3) * 8;
        if (ci < 8) {
            gP[j] = xb + (size_t)(m0 + rr) * K + ko;
            lP[j] = &smem[ci * 512];
        } else {
            const int cb = ci - 8;
            gP[j] = Wall + (size_t)(n0 + cb * 16 + (lane >> 2)) * K + ko;
            lP[j] = &smem[4096 + cb * 512];
        }
    }

    const int fr = lane & 15;
    const int fk = (lane >> 4) * 8;

    auto stage = [&](int buf, int k0) {
        const int off = buf * 12288;
#pragma unroll
        for (int j = 0; j < 3; ++j) {
            gload16(gP[j] + k0,      lP[j] + off);
            gload16(gP[j] + k0 + 32, lP[j] + off + 6144);
        }
    };

    stage(0, 0);
    __syncthreads();                         // drain prologue loads
    int cur = 0;
    for (int k0 = 0; k0 < K; k0 += 64) {
        if (k0 + 64 < K) stage(cur ^ 1, k0 + 64);
        const int off = cur * 12288;
#pragma unroll
        for (int half = 0; half < 2; ++half) {
            const int base = off + half * 6144;
            bf16x8 af[2], bf[4];
#pragma unroll
            for (int mt = 0; mt < 2; ++mt)
                af[mt] = *(const bf16x8*)&smem[base + (w * 32 + mt * 16 + fr) * 32 + fk];
#pragma unroll
            for (int nt = 0; nt < 4; ++nt)
                bf[nt] = *(const bf16x8*)&smem[base + 4096 + (nt * 16 + fr) * 32 + fk];
#pragma unroll
            for (int mt = 0; mt < 2; ++mt)
#pragma unroll
                for (int nt = 0; nt < 4; ++nt)
                    acc[mt][nt] = __builtin_amdgcn_mfma_f32_16x16x32_bf16(
                        af[mt], bf[nt], acc[mt][nt], 0, 0, 0);
        }
        __syncthreads();
        cur ^= 1;
    }

    // ---- epilogue: stage 128x64 bf16 tile (stride 72), stream coalesced ----
#pragma unroll
    for (int mt = 0; mt < 2; ++mt)
#pragma unroll
        for (int nt = 0; nt < 4; ++nt) {
            const int col = nt * 16 + fr;
#pragma unroll
            for (int r = 0; r < 4; ++r) {
                const int rw = w * 32 + mt * 16 + (lane >> 4) * 4 + r;
                smem[rw * 72 + col] = f2bf(acc[mt][nt][r]);
            }
        }
    __syncthreads();
#pragma unroll
    for (int it = 0; it < 4; ++it) {
        const int j = it * 256 + tid;       // 0..1023 chunks of 8
        const int row = j >> 3, c8 = (j & 7) * 8;
        const int m = m0 + row;
        const int b = m >> 11, c = m & (C_ - 1);
        *(u16x8*)&Out[(((size_t)(b * H_ + h) * C_ + c) << 6) + c8] =
            *(const u16x8*)&smem[row * 72 + c8];
    }
}

// ---------------------------------------------------------------------------
// GEMM 2 (MFMA bf16), 128x64 tiles, BK=64, double-buffered prefetch.
// united (4096x512) @ Wu^T-rows (1024x512) + bu -> new_out fp32
// ---------------------------------------------------------------------------
__global__ __launch_bounds__(256) void gemm_out_kernel(
    const uint16_t* __restrict__ U, const uint16_t* __restrict__ Wut,
    const float* __restrict__ bu, float* __restrict__ out)
{
    const int K = HD_;                      // 512
    const int m0 = blockIdx.y * 128;
    const int n0 = blockIdx.x * 64;         // N=1024

    __shared__ __align__(16) uint16_t smem[24576];   // 48 KB double buffer

    const int tid = threadIdx.x;
    const int w = tid >> 6, lane = tid & 63;

    f32x4 acc[2][4] = {};

    const uint16_t* gP[3];
    uint16_t* lP[3];
#pragma unroll
    for (int j = 0; j < 3; ++j) {
        const int ci = w * 3 + j;
        const int ko = (lane & 3) * 8;
        if (ci < 8) {
            gP[j] = U + (size_t)(m0 + ci * 16 + (lane >> 2)) * K + ko;
            lP[j] = &smem[ci * 512];
        } else {
            const int cb = ci - 8;
            gP[j] = Wut + (size_t)(n0 + cb * 16 + (lane >> 2)) * K + ko;
            lP[j] = &smem[4096 + cb * 512];
        }
    }

    const int fr = lane & 15;
    const int fk = (lane >> 4) * 8;

    auto stage = [&](int buf, int k0) {
        const int off = buf * 12288;
#pragma unroll
        for (int j = 0; j < 3; ++j) {
            gload16(gP[j] + k0,      lP[j] + off);
            gload16(gP[j] + k0 + 32, lP[j] + off + 6144);
        }
    };

    stage(0, 0);
    __syncthreads();
    int cur = 0;
    for (int k0 = 0; k0 < K; k0 += 64) {
        if (k0 + 64 < K) stage(cur ^ 1, k0 + 64);
        const int off = cur * 12288;
#pragma unroll
        for (int half = 0; half < 2; ++half) {
            const int base = off + half * 6144;
            bf16x8 af[2], bf[4];
#pragma unroll
            for (int mt = 0; mt < 2; ++mt)
                af[mt] = *(const bf16x8*)&smem[base + (w * 32 + mt * 16 + fr) * 32 + fk];
#pragma unroll
            for (int nt = 0; nt < 4; ++nt)
                bf[nt] = *(const bf16x8*)&smem[base + 4096 + (nt * 16 + fr) * 32 + fk];
#pragma unroll
            for (int mt = 0; mt < 2; ++mt)
#pragma unroll
                for (int nt = 0; nt < 4; ++nt)
                    acc[mt][nt] = __builtin_amdgcn_mfma_f32_16x16x32_bf16(
                        af[mt], bf[nt], acc[mt][nt], 0, 0, 0);
        }
        __syncthreads();
        cur ^= 1;
    }

#pragma unroll
    for (int mt = 0; mt < 2; ++mt) {
#pragma unroll
        for (int nt = 0; nt < 4; ++nt) {
            const int n = n0 + nt * 16 + fr;
            const float bias = bu[n];
#pragma unroll
            for (int r = 0; r < 4; ++r) {
                const int m = m0 + w * 32 + mt * 16 + (lane >> 4) * 4 + r;
                out[(size_t)m * E_ + n] = acc[mt][nt][r] + bias;
            }
        }
    }
}

// ---------------------------------------------------------------------------
// attention core (best measured config: XCD swizzle + early gather issue;
// near the 268 MB dense-write floor).
// ---------------------------------------------------------------------------
__global__ __launch_bounds__(256) void attn_kernel(
    const float* __restrict__ means, const float* __restrict__ sigmas,
    const float* __restrict__ values, const float* __restrict__ S,
    const uint16_t* __restrict__ Qt, const uint16_t* __restrict__ Kt,
    const uint16_t* __restrict__ Vt, uint16_t* __restrict__ united,
    float* __restrict__ attn)
{
    __shared__ float rowbuf[4][2048];
    const int w = threadIdx.x >> 6;
    const int lane = threadIdx.x & 63;
    const int bid = blockIdx.x;
    const int swz = (bid & 7) * 1024 + (bid >> 3);
    const int row = swz * 4 + w;
    const int bh = row >> 11;
    const int c = row & (C_ - 1);
    const int b = bh >> 3;
    const int h = bh & 7;

    const float* mrow = means + (size_t)row * 8;
    const float4 ma = *(const float4*)(mrow);
    const float4 mb = *(const float4*)(mrow + 4);
    const float mm[8] = {ma.x, ma.y, ma.z, ma.w, mb.x, mb.y, mb.z, mb.w};

    int idx[16];
#pragma unroll
    for (int j = 0; j < 8; ++j) {
        int i0 = (int)floorf(mm[j]);
        i0 = min(max(i0, 0), C_ - 1);
        idx[2 * j] = i0;
        idx[2 * j + 1] = min(i0 + 1, C_ - 1);
    }

    // ---- (p,g) layout: p = point (lane>>2), g = quarter (lane&3) ----
    const int p = lane >> 2, g = lane & 3;
    int kidx = 0;
#pragma unroll
    for (int q = 0; q < 16; ++q)
        if (q == p) kidx = idx[q];

    // ---- EARLY ISSUE: all global gathers, addresses depend only on idx ----
    const uint16_t* Qrow = Qt + ((size_t)row << 6);
    const uint16_t* Krow = Kt + ((((size_t)bh << 11) + kidx) << 6);
    const u16x8 qa = *(const u16x8*)(Qrow + g * 16);
    const u16x8 qb = *(const u16x8*)(Qrow + g * 16 + 8);
    const u16x8 ka = *(const u16x8*)(Krow + g * 16);
    const u16x8 kb = *(const u16x8*)(Krow + g * 16 + 8);
    const uint16_t* Vbh = Vt + ((size_t)bh << 17);
    uint16_t vv[16];
#pragma unroll
    for (int q = 0; q < 16; ++q)
        vv[q] = Vbh[((size_t)idx[q] << 6) + lane];

    // duplicate-point check for own p (wave-uniform idx[] in registers)
    bool dup = false;
#pragma unroll
    for (int q = 0; q < 15; ++q)
        dup = dup || ((q < p) && (idx[q] == kidx));

    // ---- per-point weight, parallel over (p, kk): lane handles kk=g,g+4 ----
    float mA = 0.f, mB = 0.f;
#pragma unroll
    for (int q = 0; q < 4; ++q)
        if (q == g) { mA = mm[q]; mB = mm[q + 4]; }
    const float* srow = sigmas + (size_t)row * 8;
    const float* vrow = values + (size_t)row * 8;
    const float* Sp = S + bh * 128 + p * 8;
    const float sgA = srow[g], sgB = srow[g + 4];
    const float vlA = vrow[g], vlB = vrow[g + 4];
    const float SvA = Sp[g],   SvB = Sp[g + 4];
    const float fi = (float)kidx;
    const float tA = (fi - mA) / sgA;
    const float tB = (fi - mB) / sgB;
    const float eA = expf(-0.5f * tA * tA);
    const float eB = expf(-0.5f * tB * tB);
    float wp = dup ? 0.0f
                   : fmaf(vlA, eA / (SvA + 1e-8f), vlB * eB / (SvB + 1e-8f));
    wp += __shfl_xor(wp, 1);
    wp += __shfl_xor(wp, 2);          // wp == wvp, replicated in 4-lane group

    // ---- Q.K dot: lane covers dims [g*16, g*16+16) of point p ----
    float dot = 0.0f;
#pragma unroll
    for (int j = 0; j < 8; ++j) {
        dot = fmaf(bf2f(qa[j]), bf2f(ka[j]), dot);
        dot = fmaf(bf2f(qb[j]), bf2f(kb[j]), dot);
    }
    dot += __shfl_xor(dot, 1);
    dot += __shfl_xor(dot, 2);

    const float logit = wp * dot;

    float mx = logit;
#pragma unroll
    for (int off = 4; off < 64; off <<= 1)
        mx = fmaxf(mx, __shfl_xor(mx, off));
    const float e = expf(logit - mx);
    float se = e;
#pragma unroll
    for (int off = 4; off < 64; off <<= 1)
        se += __shfl_xor(se, off);
    const float sm = e / se;

    float smv[16];
#pragma unroll
    for (int q = 0; q < 16; ++q)
        smv[q] = __shfl(sm, q * 4);

    // ---- V combine (lane = d) with preloaded vv ----
    float acc = 0.0f;
#pragma unroll
    for (int q = 0; q < 16; ++q)
        acc = fmaf(bf2f(vv[q]), smv[q], acc);
    united[((size_t)(b * C_ + c)) * HD_ + h * 64 + lane] = f2bf(acc);

    // ---- attentions row: zero LDS, scatter-add, nontemporal stream out ----
    const f32x4 z4 = {0.f, 0.f, 0.f, 0.f};
#pragma unroll
    for (int j = 0; j < 8; ++j)
        *(f32x4*)&rowbuf[w][(j * 64 + lane) * 4] = z4;
    __syncthreads();
    if (g == 0) atomicAdd(&rowbuf[w][kidx], sm);   // one lane per point p
    __syncthreads();
    float* arow = attn + ((size_t)row << 11);
#pragma unroll
    for (int j = 0; j < 8; ++j) {
        const int o = (j * 64 + lane) * 4;
        __builtin_nontemporal_store(*(const f32x4*)&rowbuf[w][o], (f32x4*)&arow[o]);
    }
}

// ---------------------------------------------------------------------------
// Final configuration (= R6, best measured 379.6 us).
// Attribution (R7 duplication experiment): pipeline ~116 us warm vs ~95-100
// traffic floor; remaining ~255 us of the bench window is harness poison
// fill (1.14 GB @ 80% HBM peak) + resets, outside kernel_launch's control.
// ---------------------------------------------------------------------------
extern "C" void kernel_launch(void* const* d_in, const int* in_sizes, int n_in,
                              void* d_out, int out_size, void* d_ws,
                              size_t ws_size, hipStream_t stream) {
    const float* x      = (const float*)d_in[0];
    const float* means  = (const float*)d_in[2];
    const float* sigmas = (const float*)d_in[3];
    const float* values = (const float*)d_in[4];
    const float* Wk     = (const float*)d_in[5];
    const float* Wq     = (const float*)d_in[6];
    const float* Wv     = (const float*)d_in[7];
    const float* Wu     = (const float*)d_in[8];
    const float* bu     = (const float*)d_in[9];

    float* out  = (float*)d_out;
    float* attn = out + (size_t)M_ * E_;

    uint16_t* wsp = (uint16_t*)d_ws;
    uint16_t* xb     = wsp;                              // 4194304
    uint16_t* Wall   = xb + 4194304;                     // 1572864 (1536x1024)
    uint16_t* Wut    = Wall + 1572864;                   // 524288
    uint16_t* Qt     = Wut + 524288;                     // 2097152
    uint16_t* Kt     = Qt + 2097152;
    uint16_t* Vt     = Kt + 2097152;
    uint16_t* united = Vt + 2097152;                     // 2097152
    float*    S      = (float*)(united + 2097152);       // 2048 floats

    (void)hipMemsetAsync(S, 0, 2048 * sizeof(float), stream);

    prep_kernel<<<4224, 256, 0, stream>>>(
        x, Wq, Wk, Wv, Wu, means, sigmas, xb, Wall, Wut, S);
    gemm_qkv_kernel<<<dim3(24, 32), 256, 0, stream>>>(xb, Wall, Qt, Kt, Vt);
    attn_kernel<<<ROWS_ / 4, 256, 0, stream>>>(
        means, sigmas, values, S, Qt, Kt, Vt, united, attn);
    gemm_out_kernel<<<dim3(16, 32), 256, 0, stream>>>(united, Wut, bu, out);
}